// Round 1
// 190.113 us; speedup vs baseline: 1.0029x; 1.0029x over previous
//
#include <hip/hip_runtime.h>

#define N_TOK 16384
#define DIM   1024
#define PATHS 8
#define CAP   4096
#define TPB   256
#define NBLK  (N_TOK / TPB)   // 64 routing blocks

// ---- workspace layout (bytes) ----
// blockCnt: 64*8 ints                 = 2048
// pg      : 16384 int2 {path, gate}   = 131072
// rec     : 8*4096 int2 {tok, gate}   = 262144
#define OFF_BCNT 0
#define OFF_PG   2048
#define OFF_REC  (2048 + N_TOK * 8)

// A1: per-token argmax/max + per-block path histogram.
// Packs {path, gate_bits} into one int2 store (was two separate arrays).
__global__ void k_route(const float* __restrict__ scores,
                        int2* __restrict__ pg,
                        int* __restrict__ blockCnt) {
    __shared__ int cnt[PATHS];
    int tid = threadIdx.x;
    if (tid < PATHS) cnt[tid] = 0;
    __syncthreads();
    int t = blockIdx.x * TPB + tid;
    const float4* s4 = (const float4*)scores;
    float4 s0 = s4[t * 2];
    float4 s1 = s4[t * 2 + 1];
    float best = s0.x; int bp = 0;
    if (s0.y > best) { best = s0.y; bp = 1; }
    if (s0.z > best) { best = s0.z; bp = 2; }
    if (s0.w > best) { best = s0.w; bp = 3; }
    if (s1.x > best) { best = s1.x; bp = 4; }
    if (s1.y > best) { best = s1.y; bp = 5; }
    if (s1.z > best) { best = s1.z; bp = 6; }
    if (s1.w > best) { best = s1.w; bp = 7; }
    pg[t] = make_int2(bp, __float_as_int(best));
    atomicAdd(&cnt[bp], 1);
    __syncthreads();
    if (tid < PATHS) blockCnt[blockIdx.x * PATHS + tid] = cnt[tid];
}

// A2: slot assignment. Each block redundantly scans the tiny 64x8 histogram
// (2 KB, L2-resident) for its per-path exclusive base (measured best: no
// separate scan kernel, no spin barrier). Writes packed rec {tok, gate_bits}
// and tail-fills rec.x = -1 for empty slots so the gather needs NO counts
// lookup (shortens its dependent-load chain by two L2 hops).
__global__ void k_slot(const int2* __restrict__ pg,
                       const int* __restrict__ blockCnt,
                       int2* __restrict__ rec) {
    __shared__ int sBase[PATHS];
    __shared__ int sCnt[PATHS];
    __shared__ int wcnt[4 * PATHS];
    __shared__ int woff[4 * PATHS];
    int tid = threadIdx.x;
    if (tid < PATHS) {
        int p = tid;
        int run = 0, mine = 0;
        #pragma unroll
        for (int b = 0; b < NBLK; ++b) {
            if (b == (int)blockIdx.x) mine = run;
            run += blockCnt[b * PATHS + p];
        }
        sBase[p] = mine;
        sCnt[p] = run;
    }
    int t = blockIdx.x * TPB + tid;
    int2 pgv = pg[t];
    int p = pgv.x;
    int lane = tid & 63;
    int wv = tid >> 6;
    unsigned long long lt_mask = (1ULL << lane) - 1ULL;
    int rank = 0;
    #pragma unroll
    for (int q = 0; q < PATHS; ++q) {
        unsigned long long m = __ballot(p == q);
        if (p == q) rank = __popcll(m & lt_mask);
        if (lane == 0) wcnt[wv * PATHS + q] = __popcll(m);
    }
    __syncthreads();
    if (tid < PATHS) {
        int run = 0;
        for (int w = 0; w < 4; ++w) {
            woff[w * PATHS + tid] = run;
            run += wcnt[w * PATHS + tid];
        }
    }
    __syncthreads();
    int slot = sBase[p] + woff[wv * PATHS + p] + rank;
    if (slot < CAP) rec[p * CAP + slot] = make_int2(t, pgv.y);
    // Tail-fill: mark empty slots invalid. Each block covers a disjoint
    // 512-slot stripe of the 32768 rows; valid writes (s < cnt) and fills
    // (s >= cnt) never overlap, so cross-block order is irrelevant.
    #pragma unroll
    for (int k = 0; k < 2; ++k) {
        int sl = blockIdx.x * (PATHS * CAP / NBLK) + k * TPB + tid;
        int pp = sl >> 12;
        int ss = sl & (CAP - 1);
        if (ss >= sCnt[pp]) rec[sl] = make_int2(-1, 0);
    }
}

// B: dense gather into output. One block per output row (p, s); 256 threads
// x float4 = 1024 floats (measured best: RPB=1; RPB=8 regressed). Single
// 8-byte uniform rec load replaces the old counts->inv->gval chain.
__global__ void k_gather(const float* __restrict__ x,
                         const int2* __restrict__ rec,
                         float* __restrict__ out) {
    int row = blockIdx.x;              // 0 .. PATHS*CAP-1
    int tid = threadIdx.x;
    int2 r = rec[row];                 // uniform -> one s_load_dwordx2
    float4* orow = (float4*)(out + (size_t)row * DIM);
    float4 v;
    if (r.x >= 0) {
        float g = __int_as_float(r.y);
        const float4* xrow = (const float4*)(x + (size_t)r.x * DIM);
        v = xrow[tid];
        v.x *= g; v.y *= g; v.z *= g; v.w *= g;
    } else {
        v = make_float4(0.f, 0.f, 0.f, 0.f);
    }
    orow[tid] = v;
}

extern "C" void kernel_launch(void* const* d_in, const int* in_sizes, int n_in,
                              void* d_out, int out_size, void* d_ws, size_t ws_size,
                              hipStream_t stream) {
    const float* x      = (const float*)d_in[0];
    const float* scores = (const float*)d_in[1];
    float* out = (float*)d_out;
    char* ws = (char*)d_ws;

    int*  blockCnt = (int*) (ws + OFF_BCNT);
    int2* pg       = (int2*)(ws + OFF_PG);
    int2* rec      = (int2*)(ws + OFF_REC);

    k_route<<<NBLK, TPB, 0, stream>>>(scores, pg, blockCnt);
    k_slot<<<NBLK, TPB, 0, stream>>>(pg, blockCnt, rec);
    k_gather<<<PATHS * CAP, TPB, 0, stream>>>(x, rec, out);
}